// Round 10
// baseline (458.716 us; speedup 1.0000x reference)
//
#include <hip/hip_runtime.h>
#include <hip/hip_bf16.h>

#define N_ROWS 16384
#define M_ROWS 16384
#define DIM 256
#define JT 32           // y-cols per j-iter
#define NJ 64           // j-iters per block (JT*NJ = 2048-col chunk)

typedef __attribute__((ext_vector_type(4))) float f32x4;
typedef __attribute__((ext_vector_type(8))) short bf16x8;

__device__ inline unsigned enc_f(float f) {
  unsigned u = __float_as_uint(f);
  return (u & 0x80000000u) ? ~u : (u | 0x80000000u);
}
__device__ inline float dec_f(unsigned u) {
  unsigned b = (u & 0x80000000u) ? (u & 0x7FFFFFFFu) : ~u;
  return __uint_as_float(b);
}
__device__ inline unsigned short f2bf(float f) {
  unsigned u = __float_as_uint(f);
  u += 0x7FFFu + ((u >> 16) & 1u);
  return (unsigned short)(u >> 16);
}

// Fused prep: blocks [0,4096) convert x -> xb (row-major) + x2 + rowmin init;
// blocks [4096,8192) convert y -> yb2 (fragment-major tiles) + (y2 - psi).
// yb2 layout: tile t = (row>>4)*8 + (k>>5); within tile (512 shorts):
// off = (row&15)*32 + (k&31). One tile = the 16x32 B-fragment for one
// (16-col group, 32-k slice) -> gemm reads it as ONE coalesced 1-KB load.
__global__ __launch_bounds__(256) void prep_kernel(
    const float* __restrict__ x, const float* __restrict__ y,
    const float* __restrict__ psi,
    unsigned short* __restrict__ xb, unsigned short* __restrict__ yb2,
    float* __restrict__ x2, float* __restrict__ rj,
    unsigned int* __restrict__ rowmin) {
  int bid  = blockIdx.x;
  int isY  = bid >= (N_ROWS / 4);
  int rb   = isY ? bid - N_ROWS / 4 : bid;
  int row  = rb * 4 + (threadIdx.x >> 6);
  int lane = threadIdx.x & 63;
  const float* in = isY ? y : x;
  const float4 v = *reinterpret_cast<const float4*>(in + (size_t)row * DIM + lane * 4);
  ushort4 b;
  b.x = f2bf(v.x); b.y = f2bf(v.y); b.z = f2bf(v.z); b.w = f2bf(v.w);
  if (isY) {
    int k0   = lane * 4;                       // 0..252
    int tile = (row >> 4) * 8 + (k0 >> 5);
    int off  = (row & 15) * 32 + (k0 & 31);    // shorts within tile
    *reinterpret_cast<ushort4*>(yb2 + (size_t)tile * 512 + off) = b;
  } else {
    *reinterpret_cast<ushort4*>(xb + (size_t)row * DIM + lane * 4) = b;
  }
  float s = v.x * v.x + v.y * v.y + v.z * v.z + v.w * v.w;
#pragma unroll
  for (int m = 1; m < 64; m <<= 1) s += __shfl_xor(s, m, 64);
  if (lane == 0) {
    if (isY) rj[row] = s - psi[row];
    else { x2[row] = s; rowmin[row] = 0xFFFFFFFFu; }
  }
}

// Register-resident-A (64 rows/wave, AGPR-pinned), M-streaming GEMM+min.
// NO LDS, NO barriers: B fragments stream L1/L2 -> registers via coalesced
// 1-KB tile loads, double-buffered one j-iter ahead. Waves free-run.
// Block: 4 waves (256 thr), 256 x-rows x 2048 y-cols; 64 j-iters of 32 cols.
__global__ __launch_bounds__(256, 2) void gemm_min_kernel(
    const unsigned short* __restrict__ xb, const unsigned short* __restrict__ yb2,
    const float* __restrict__ rj, unsigned int* __restrict__ rowmin) {
  const int bid    = blockIdx.x;       // 512 blocks, 2 per CU
  const int jchunk = bid & 7;          // == XCD id under round-robin dispatch
  const int strip  = bid >> 3;         // 0..63
  const int brow   = strip * 256;
  const int jbase0 = jchunk * (JT * NJ);

  const int tid = threadIdx.x;
  const int w = tid >> 6, lane = tid & 63;
  const int fr = lane & 15, g4 = lane >> 4;

  // ---- A fragments: rows brow + w*64 + m*16 + fr, k = ks*32 + g4*8; AGPR-pinned.
  bf16x8 afr[4][8];
  {
    const unsigned short* aBase = xb + (size_t)(brow + w * 64 + fr) * DIM + g4 * 8;
#pragma unroll
    for (int m = 0; m < 4; ++m)
#pragma unroll
      for (int ks = 0; ks < 8; ++ks) {
        afr[m][ks] = *reinterpret_cast<const bf16x8*>(aBase + (size_t)(m * 16) * DIM + ks * 32);
        asm volatile("" : "+a"(afr[m][ks]));  // pin in AGPR file
      }
  }
  __builtin_amdgcn_sched_barrier(0);

  // ---- B tile base for this chunk; lane slot within each 1-KB tile.
  const unsigned short* btiles = yb2 + (size_t)(jbase0 >> 4) * 8 * 512;
  const int lslot = fr * 32 + g4 * 8;  // shorts

  // LOADB(dst, jj): 16 coalesced dwordx4 loads = B fragments for j-iter jj
  // (two 16-col groups x 8 k-slices). dst[n*8+ks].
#define LOADB(dst, jj)                                                          \
  {                                                                             \
    const unsigned short* tb = btiles + (size_t)(jj) * 16 * 512;                \
    _Pragma("unroll")                                                           \
    for (int n = 0; n < 2; ++n)                                                 \
      _Pragma("unroll")                                                         \
      for (int ks = 0; ks < 8; ++ks)                                            \
        dst[n * 8 + ks] = *reinterpret_cast<const bf16x8*>(                     \
            tb + (n * 8 + ks) * 512 + lslot);                                   \
  }

#define MFMA_FOLD(bsrc, rv0, rv1)                                               \
  {                                                                             \
    f32x4 acc[4][2];                                                            \
    _Pragma("unroll")                                                           \
    for (int m = 0; m < 4; ++m)                                                 \
      _Pragma("unroll")                                                         \
      for (int n = 0; n < 2; ++n) acc[m][n] = (f32x4){0.f, 0.f, 0.f, 0.f};      \
    __builtin_amdgcn_s_setprio(1);                                              \
    _Pragma("unroll")                                                           \
    for (int ks = 0; ks < 8; ++ks)                                              \
      _Pragma("unroll")                                                         \
      for (int m = 0; m < 4; ++m) {                                             \
        acc[m][0] = __builtin_amdgcn_mfma_f32_16x16x32_bf16(                    \
            afr[m][ks], bsrc[ks], acc[m][0], 0, 0, 0);                          \
        acc[m][1] = __builtin_amdgcn_mfma_f32_16x16x32_bf16(                    \
            afr[m][ks], bsrc[8 + ks], acc[m][1], 0, 0, 0);                      \
      }                                                                         \
    __builtin_amdgcn_s_setprio(0);                                              \
    _Pragma("unroll")                                                           \
    for (int m = 0; m < 4; ++m)                                                 \
      _Pragma("unroll")                                                         \
      for (int r = 0; r < 4; ++r) {                                             \
        mn[m][r] = fminf(mn[m][r], fmaf(-2.f, acc[m][0][r], rv0));              \
        mn[m][r] = fminf(mn[m][r], fmaf(-2.f, acc[m][1][r], rv1));              \
      }                                                                         \
  }

  const float* rjc = rj + jbase0;
  float mn[4][4];
#pragma unroll
  for (int m = 0; m < 4; ++m)
#pragma unroll
    for (int r = 0; r < 4; ++r) mn[m][r] = 3.4e38f;

  bf16x8 ba[16], bb[16];
  float rva0, rva1, rvb0, rvb1;
  rva0 = rjc[fr]; rva1 = rjc[16 + fr];
  LOADB(ba, 0);

#pragma unroll 1
  for (int j = 0; j < NJ; j += 2) {
    // prefetch rv+B for iter j+1 (rv first so fold's waitcnt keeps B in flight)
    rvb0 = rjc[(j + 1) * JT + fr];
    rvb1 = rjc[(j + 1) * JT + 16 + fr];
    LOADB(bb, j + 1);
    __builtin_amdgcn_sched_barrier(0);
    MFMA_FOLD(ba, rva0, rva1);

    // prefetch rv+B for iter j+2 (clamped on last pass; values unused)
    {
      int j2 = (j + 2 < NJ) ? j + 2 : NJ - 1;
      rva0 = rjc[j2 * JT + fr];
      rva1 = rjc[j2 * JT + 16 + fr];
      LOADB(ba, j2);
    }
    __builtin_amdgcn_sched_barrier(0);
    MFMA_FOLD(bb, rvb0, rvb1);
  }
#undef LOADB
#undef MFMA_FOLD

  // Row-min over chunk: reduce min over the 16 fr-lanes, then one atomic per row.
#pragma unroll
  for (int m = 0; m < 4; ++m)
#pragma unroll
    for (int r = 0; r < 4; ++r) {
      float v = mn[m][r];
#pragma unroll
      for (int s = 1; s < 16; s <<= 1) v = fminf(v, __shfl_xor(v, s, 64));
      if (fr == 0) {
        int row = brow + w * 64 + m * 16 + g4 * 4 + r;
        atomicMin(&rowmin[row], enc_f(v));
      }
    }
}

__global__ __launch_bounds__(256) void finish_kernel(
    const float* __restrict__ x2, const unsigned int* __restrict__ rowmin,
    const float* __restrict__ psi, float* __restrict__ out) {
  int tid = threadIdx.x;
  double s0 = 0.0, s1 = 0.0;
  for (int i = tid; i < N_ROWS; i += 256) {
    s0 += (double)x2[i] + (double)dec_f(rowmin[i]);
    s1 += (double)psi[i];
  }
  __shared__ double sm0[4], sm1[4];
#pragma unroll
  for (int m = 1; m < 64; m <<= 1) { s0 += __shfl_xor(s0, m, 64); s1 += __shfl_xor(s1, m, 64); }
  if ((tid & 63) == 0) { sm0[tid >> 6] = s0; sm1[tid >> 6] = s1; }
  __syncthreads();
  if (tid == 0) {
    out[0] = (float)((sm0[0] + sm0[1] + sm0[2] + sm0[3]) / (double)N_ROWS);
    out[1] = (float)((sm1[0] + sm1[1] + sm1[2] + sm1[3]) / (double)M_ROWS);
  }
}

extern "C" void kernel_launch(void* const* d_in, const int* in_sizes, int n_in,
                              void* d_out, int out_size, void* d_ws, size_t ws_size,
                              hipStream_t stream) {
  const float* x   = (const float*)d_in[0];
  const float* y   = (const float*)d_in[1];
  const float* psi = (const float*)d_in[2];
  float* out = (float*)d_out;

  char* ws = (char*)d_ws;
  unsigned short* xb  = (unsigned short*)ws;                                 // 8 MB
  unsigned short* yb2 = (unsigned short*)(ws + (size_t)N_ROWS * DIM * 2);    // 8 MB (tiled)
  float* x2 = (float*)(ws + (size_t)(N_ROWS + M_ROWS) * DIM * 2);            // 64 KB
  float* rj = x2 + N_ROWS;                                                   // 64 KB (y2 - psi)
  unsigned int* rowmin = (unsigned int*)(rj + M_ROWS);                       // 64 KB

  prep_kernel<<<(N_ROWS + M_ROWS) / 4, 256, 0, stream>>>(x, y, psi, xb, yb2, x2, rj, rowmin);
  gemm_min_kernel<<<(N_ROWS / 256) * 8, 256, 0, stream>>>(xb, yb2, rj, rowmin);
  finish_kernel<<<1, 256, 0, stream>>>(x2, rowmin, psi, out);
}

// Round 11
// 140.644 us; speedup vs baseline: 3.2615x; 3.2615x over previous
//
#include <hip/hip_runtime.h>
#include <hip/hip_bf16.h>

#define N_ROWS 16384
#define M_ROWS 16384
#define DIM 256
#define JT 32           // y-cols per j-iter
#define NJ 64           // j-iters per block (JT*NJ = 2048-col chunk)

typedef __attribute__((ext_vector_type(4))) float f32x4;
typedef __attribute__((ext_vector_type(8))) short bf16x8;

__device__ inline unsigned enc_f(float f) {
  unsigned u = __float_as_uint(f);
  return (u & 0x80000000u) ? ~u : (u | 0x80000000u);
}
__device__ inline float dec_f(unsigned u) {
  unsigned b = (u & 0x80000000u) ? (u & 0x7FFFFFFFu) : ~u;
  return __uint_as_float(b);
}
__device__ inline unsigned short f2bf(float f) {
  unsigned u = __float_as_uint(f);
  u += 0x7FFFu + ((u >> 16) & 1u);
  return (unsigned short)(u >> 16);
}

// Fused prep: blocks [0,4096) convert x -> xb + x2 + rowmin init;
// blocks [4096,8192) convert y -> yb + (y2 - psi).
__global__ __launch_bounds__(256) void prep_kernel(
    const float* __restrict__ x, const float* __restrict__ y,
    const float* __restrict__ psi,
    unsigned short* __restrict__ xb, unsigned short* __restrict__ yb,
    float* __restrict__ x2, float* __restrict__ rj,
    unsigned int* __restrict__ rowmin) {
  int bid  = blockIdx.x;
  int isY  = bid >= (N_ROWS / 4);
  int rb   = isY ? bid - N_ROWS / 4 : bid;
  int row  = rb * 4 + (threadIdx.x >> 6);
  int lane = threadIdx.x & 63;
  const float* in = isY ? y : x;
  unsigned short* outb = isY ? yb : xb;
  const float4 v = *reinterpret_cast<const float4*>(in + (size_t)row * DIM + lane * 4);
  ushort4 b;
  b.x = f2bf(v.x); b.y = f2bf(v.y); b.z = f2bf(v.z); b.w = f2bf(v.w);
  *reinterpret_cast<ushort4*>(outb + (size_t)row * DIM + lane * 4) = b;
  float s = v.x * v.x + v.y * v.y + v.z * v.z + v.w * v.w;
#pragma unroll
  for (int m = 1; m < 64; m <<= 1) s += __shfl_xor(s, m, 64);
  if (lane == 0) {
    if (isY) rj[row] = s - psi[row];
    else { x2[row] = s; rowmin[row] = 0xFFFFFFFFu; }
  }
}

// Register-resident-A (64 rows/wave, AGPR-pinned), M-streaming GEMM+min.
// Block: 4 waves (256 thr), 256 x-rows x 2048 y-cols; 64 j-iters of 32 cols.
// B: 3-deep LDS ring (16KB tiles), counted vmcnt(4), raw s_barrier, stage j+2.
// ks-loop: 2-deep B-fragment ring + sched_group_barrier {2 DS_READ, 8 MFMA}
// pinning so ds_reads ride UNDER the MFMA clusters (defeats load clustering).
__global__ __launch_bounds__(256, 2) void gemm_min_kernel(
    const unsigned short* __restrict__ xb, const unsigned short* __restrict__ yb,
    const float* __restrict__ rj, unsigned int* __restrict__ rowmin) {
  __shared__ unsigned short Bt[3][JT * DIM];  // 3 x 16 KiB, 16B-slot XOR swizzle

  const int bid    = blockIdx.x;       // 512 blocks, 2 per CU
  const int jchunk = bid & 7;          // == XCD id under round-robin dispatch
  const int strip  = bid >> 3;         // 0..63
  const int brow   = strip * 256;
  const int jbase0 = jchunk * (JT * NJ);

  const int tid = threadIdx.x;
  const int w = tid >> 6, lane = tid & 63;
  const int fr = lane & 15, g4 = lane >> 4;

  // ---- A fragments: rows brow + w*64 + m*16 + fr, k = ks*32 + g4*8; AGPR-pinned.
  bf16x8 afr[4][8];
  {
    const unsigned short* aBase = xb + (size_t)(brow + w * 64 + fr) * DIM + g4 * 8;
#pragma unroll
    for (int m = 0; m < 4; ++m)
#pragma unroll
      for (int ks = 0; ks < 8; ++ks) {
        afr[m][ks] = *reinterpret_cast<const bf16x8*>(aBase + (size_t)(m * 16) * DIM + ks * 32);
        asm volatile("" : "+a"(afr[m][ks]));  // pin in AGPR file
      }
  }
  __builtin_amdgcn_sched_barrier(0);

  // ---- staging: wave w stages B rows w*8 + c*2 + (lane>>5); 4 instrs x 1KB.
  // LDS[row][slot] = global[row][slot ^ (row&7)]  (16B slots, 32/row)
  const unsigned short* gBrow = yb + (size_t)(jbase0 + w * 8 + (lane >> 5)) * DIM;

#define STAGE(buf, j)                                                            \
  {                                                                              \
    const unsigned short* gb = gBrow + (size_t)(j) * JT * DIM;                   \
    _Pragma("unroll")                                                            \
    for (int c = 0; c < 4; ++c) {                                                \
      int sl = (lane & 31) ^ (((lane >> 5) + c * 2) & 7);                        \
      __builtin_amdgcn_global_load_lds(                                          \
          (const __attribute__((address_space(1))) void*)(gb + (size_t)(c * 2) * DIM + sl * 8), \
          (__attribute__((address_space(3))) void*)(&Bt[(buf)][(w * 8 + c * 2) * DIM]), 16, 0, 0); \
    }                                                                            \
  }

  STAGE(0, 0);
  STAGE(1, 1);

  const float* rjc = rj + jbase0;
  float mn[4][4];
#pragma unroll
  for (int m = 0; m < 4; ++m)
#pragma unroll
    for (int r = 0; r < 4; ++r) mn[m][r] = 3.4e38f;

  int rb = 0;  // ring read index
#pragma unroll 1
  for (int j = 0; j < NJ; ++j) {
    if (j == NJ - 1) { asm volatile("s_waitcnt vmcnt(0)" ::: "memory"); }
    else             { asm volatile("s_waitcnt vmcnt(4)" ::: "memory"); }
    __builtin_amdgcn_sched_barrier(0);
    __builtin_amdgcn_s_barrier();
    __builtin_amdgcn_sched_barrier(0);

    // rv loads issued early; consumed only at iter end (latency hidden by MFMA).
    float rv0 = rjc[j * JT + fr];
    float rv1 = rjc[j * JT + 16 + fr];
    __builtin_amdgcn_sched_barrier(0);
    if (j + 2 < NJ) {
      int sb = rb + 2; if (sb >= 3) sb -= 3;
      STAGE(sb, j + 2);
    }
    __builtin_amdgcn_sched_barrier(0);

    f32x4 acc[4][2];
#pragma unroll
    for (int m = 0; m < 4; ++m)
#pragma unroll
      for (int n = 0; n < 2; ++n) acc[m][n] = (f32x4){0.f, 0.f, 0.f, 0.f};

    const unsigned short* B = &Bt[rb][0];
    // 2-deep B-fragment prefetch ring (indices compile-time after full unroll).
#define BSLOT(ks) ((((ks) * 4 + g4) ^ (fr & 7)) * 8)
    bf16x8 pb0[3], pb1[3];
    pb0[0] = *reinterpret_cast<const bf16x8*>(&B[fr * DIM + BSLOT(0)]);
    pb1[0] = *reinterpret_cast<const bf16x8*>(&B[(16 + fr) * DIM + BSLOT(0)]);
    pb0[1] = *reinterpret_cast<const bf16x8*>(&B[fr * DIM + BSLOT(1)]);
    pb1[1] = *reinterpret_cast<const bf16x8*>(&B[(16 + fr) * DIM + BSLOT(1)]);

    __builtin_amdgcn_s_setprio(1);
    __builtin_amdgcn_sched_barrier(0);
#pragma unroll
    for (int ks = 0; ks < 8; ++ks) {
      const int cs = ks % 3;
      const int ns = (ks + 2) % 3;
      if (ks < 6) {
        pb0[ns] = *reinterpret_cast<const bf16x8*>(&B[fr * DIM + BSLOT(ks + 2)]);
        pb1[ns] = *reinterpret_cast<const bf16x8*>(&B[(16 + fr) * DIM + BSLOT(ks + 2)]);
      }
#pragma unroll
      for (int m = 0; m < 4; ++m) {
        acc[m][0] = __builtin_amdgcn_mfma_f32_16x16x32_bf16(afr[m][ks], pb0[cs], acc[m][0], 0, 0, 0);
        acc[m][1] = __builtin_amdgcn_mfma_f32_16x16x32_bf16(afr[m][ks], pb1[cs], acc[m][1], 0, 0, 0);
      }
      // Pin emission: 2 ds_reads ride under each 8-MFMA cluster.
      if (ks < 6) {
        __builtin_amdgcn_sched_group_barrier(0x100, 2, 0);  // 2 DS_READ
        __builtin_amdgcn_sched_group_barrier(0x008, 8, 0);  // 8 MFMA
      } else {
        __builtin_amdgcn_sched_group_barrier(0x008, 8, 0);  // 8 MFMA
      }
    }
    __builtin_amdgcn_sched_barrier(0);
#undef BSLOT
    __builtin_amdgcn_s_setprio(0);

    // fold: val = rv - 2*dot ; running min
#pragma unroll
    for (int m = 0; m < 4; ++m)
#pragma unroll
      for (int r = 0; r < 4; ++r) {
        mn[m][r] = fminf(mn[m][r], fmaf(-2.f, acc[m][0][r], rv0));
        mn[m][r] = fminf(mn[m][r], fmaf(-2.f, acc[m][1][r], rv1));
      }
    rb = rb + 1; if (rb >= 3) rb -= 3;
  }
#undef STAGE

  // Row-min over chunk: reduce min over the 16 fr-lanes, then one atomic per row.
#pragma unroll
  for (int m = 0; m < 4; ++m)
#pragma unroll
    for (int r = 0; r < 4; ++r) {
      float v = mn[m][r];
#pragma unroll
      for (int s = 1; s < 16; s <<= 1) v = fminf(v, __shfl_xor(v, s, 64));
      if (fr == 0) {
        int row = brow + w * 64 + m * 16 + g4 * 4 + r;
        atomicMin(&rowmin[row], enc_f(v));
      }
    }
}

__global__ __launch_bounds__(256) void finish_kernel(
    const float* __restrict__ x2, const unsigned int* __restrict__ rowmin,
    const float* __restrict__ psi, float* __restrict__ out) {
  int tid = threadIdx.x;
  double s0 = 0.0, s1 = 0.0;
  for (int i = tid; i < N_ROWS; i += 256) {
    s0 += (double)x2[i] + (double)dec_f(rowmin[i]);
    s1 += (double)psi[i];
  }
  __shared__ double sm0[4], sm1[4];
#pragma unroll
  for (int m = 1; m < 64; m <<= 1) { s0 += __shfl_xor(s0, m, 64); s1 += __shfl_xor(s1, m, 64); }
  if ((tid & 63) == 0) { sm0[tid >> 6] = s0; sm1[tid >> 6] = s1; }
  __syncthreads();
  if (tid == 0) {
    out[0] = (float)((sm0[0] + sm0[1] + sm0[2] + sm0[3]) / (double)N_ROWS);
    out[1] = (float)((sm1[0] + sm1[1] + sm1[2] + sm1[3]) / (double)M_ROWS);
  }
}

extern "C" void kernel_launch(void* const* d_in, const int* in_sizes, int n_in,
                              void* d_out, int out_size, void* d_ws, size_t ws_size,
                              hipStream_t stream) {
  const float* x   = (const float*)d_in[0];
  const float* y   = (const float*)d_in[1];
  const float* psi = (const float*)d_in[2];
  float* out = (float*)d_out;

  char* ws = (char*)d_ws;
  unsigned short* xb = (unsigned short*)ws;                                  // 8 MB
  unsigned short* yb = (unsigned short*)(ws + (size_t)N_ROWS * DIM * 2);     // 8 MB
  float* x2 = (float*)(ws + (size_t)(N_ROWS + M_ROWS) * DIM * 2);            // 64 KB
  float* rj = x2 + N_ROWS;                                                   // 64 KB (y2 - psi)
  unsigned int* rowmin = (unsigned int*)(rj + M_ROWS);                       // 64 KB

  prep_kernel<<<(N_ROWS + M_ROWS) / 4, 256, 0, stream>>>(x, y, psi, xb, yb, x2, rj, rowmin);
  gemm_min_kernel<<<(N_ROWS / 256) * 8, 256, 0, stream>>>(xb, yb, rj, rowmin);
  finish_kernel<<<1, 256, 0, stream>>>(x2, rowmin, psi, out);
}

// Round 12
// 139.421 us; speedup vs baseline: 3.2901x; 1.0088x over previous
//
#include <hip/hip_runtime.h>
#include <hip/hip_bf16.h>

#define N_ROWS 16384
#define M_ROWS 16384
#define DIM 256
#define JT 32           // y-cols per j-iter
#define NJ 64           // j-iters per block (JT*NJ = 2048-col chunk)

typedef __attribute__((ext_vector_type(4))) float f32x4;
typedef __attribute__((ext_vector_type(8))) short bf16x8;

__device__ inline unsigned enc_f(float f) {
  unsigned u = __float_as_uint(f);
  return (u & 0x80000000u) ? ~u : (u | 0x80000000u);
}
__device__ inline float dec_f(unsigned u) {
  unsigned b = (u & 0x80000000u) ? (u & 0x7FFFFFFFu) : ~u;
  return __uint_as_float(b);
}
__device__ inline unsigned short f2bf(float f) {
  unsigned u = __float_as_uint(f);
  u += 0x7FFFu + ((u >> 16) & 1u);
  return (unsigned short)(u >> 16);
}

// Fused prep: blocks [0,4096) convert x -> xb + x2 + rowmin init;
// blocks [4096,8192) convert y -> yb + (y2 - psi).
__global__ __launch_bounds__(256) void prep_kernel(
    const float* __restrict__ x, const float* __restrict__ y,
    const float* __restrict__ psi,
    unsigned short* __restrict__ xb, unsigned short* __restrict__ yb,
    float* __restrict__ x2, float* __restrict__ rj,
    unsigned int* __restrict__ rowmin) {
  int bid  = blockIdx.x;
  int isY  = bid >= (N_ROWS / 4);
  int rb   = isY ? bid - N_ROWS / 4 : bid;
  int row  = rb * 4 + (threadIdx.x >> 6);
  int lane = threadIdx.x & 63;
  const float* in = isY ? y : x;
  unsigned short* outb = isY ? yb : xb;
  const float4 v = *reinterpret_cast<const float4*>(in + (size_t)row * DIM + lane * 4);
  ushort4 b;
  b.x = f2bf(v.x); b.y = f2bf(v.y); b.z = f2bf(v.z); b.w = f2bf(v.w);
  *reinterpret_cast<ushort4*>(outb + (size_t)row * DIM + lane * 4) = b;
  float s = v.x * v.x + v.y * v.y + v.z * v.z + v.w * v.w;
#pragma unroll
  for (int m = 1; m < 64; m <<= 1) s += __shfl_xor(s, m, 64);
  if (lane == 0) {
    if (isY) rj[row] = s - psi[row];
    else { x2[row] = s; rowmin[row] = 0xFFFFFFFFu; }
  }
}

// Register-resident-A (64 rows/wave, AGPR-pinned), M-streaming GEMM+min.
// Block: 4 waves (256 thr), 256 x-rows x 2048 y-cols; 64 j-iters of 32 cols.
// B: 3-deep LDS ring, counted vmcnt(4), raw s_barrier, stage j+2.
// LDS layout: FRAGMENT-MAJOR. Tile = 16 chunks x 1KB; chunk cc = n*8+ks holds
// the (16-col group n, 32-k slice ks) B-fragment as [fr][g4] 16B units ->
// each ds_read_b128 covers a contiguous 1KB span = ZERO bank conflicts.
// global_load_lds: lane-linear LDS dest, permuted per-lane GLOBAL source.
// ks-loop: 2-deep B-fragment ring + sched_group_barrier {2 DS_READ, 8 MFMA}.
__global__ __launch_bounds__(256, 2) void gemm_min_kernel(
    const unsigned short* __restrict__ xb, const unsigned short* __restrict__ yb,
    const float* __restrict__ rj, unsigned int* __restrict__ rowmin) {
  __shared__ unsigned short Bt[3][JT * DIM];  // 3 x 16 KiB

  const int bid    = blockIdx.x;       // 512 blocks, 2 per CU
  const int jchunk = bid & 7;          // == XCD id under round-robin dispatch
  const int strip  = bid >> 3;         // 0..63
  const int brow   = strip * 256;
  const int jbase0 = jchunk * (JT * NJ);

  const int tid = threadIdx.x;
  const int w = tid >> 6, lane = tid & 63;
  const int fr = lane & 15, g4 = lane >> 4;

  // ---- A fragments: rows brow + w*64 + m*16 + fr, k = ks*32 + g4*8; AGPR-pinned.
  bf16x8 afr[4][8];
  {
    const unsigned short* aBase = xb + (size_t)(brow + w * 64 + fr) * DIM + g4 * 8;
#pragma unroll
    for (int m = 0; m < 4; ++m)
#pragma unroll
      for (int ks = 0; ks < 8; ++ks) {
        afr[m][ks] = *reinterpret_cast<const bf16x8*>(aBase + (size_t)(m * 16) * DIM + ks * 32);
        asm volatile("" : "+a"(afr[m][ks]));  // pin in AGPR file
      }
  }
  __builtin_amdgcn_sched_barrier(0);

  // ---- staging: wave w stages chunks cc = w*4..w*4+3 (1KB each).
  // chunk cc = n*8 + ks; LDS[cc*1024 + lane*16] = yb[row: j*JT + n*16 + (lane>>2),
  // k: ks*32 + (lane&3)*8] -- lane-linear dest, permuted global source.
  const int srow = lane >> 2;          // 0..15 row within col-group
  const int scol = (lane & 3) * 8;     // k elems within 32-k slice

#define STAGE(buf, j)                                                            \
  {                                                                              \
    _Pragma("unroll")                                                            \
    for (int c = 0; c < 4; ++c) {                                                \
      const int cc = w * 4 + c;                                                  \
      const int sn = cc >> 3, sk = cc & 7;                                       \
      __builtin_amdgcn_global_load_lds(                                          \
          (const __attribute__((address_space(1))) void*)(                       \
              yb + (size_t)(jbase0 + (j) * JT + sn * 16 + srow) * DIM + sk * 32 + scol), \
          (__attribute__((address_space(3))) void*)(&Bt[(buf)][cc * 512]), 16, 0, 0); \
    }                                                                            \
  }

  STAGE(0, 0);
  STAGE(1, 1);

  const float* rjc = rj + jbase0;
  float mn[4][4];
#pragma unroll
  for (int m = 0; m < 4; ++m)
#pragma unroll
    for (int r = 0; r < 4; ++r) mn[m][r] = 3.4e38f;

  int rb = 0;  // ring read index
#pragma unroll 1
  for (int j = 0; j < NJ; ++j) {
    if (j == NJ - 1) { asm volatile("s_waitcnt vmcnt(0)" ::: "memory"); }
    else             { asm volatile("s_waitcnt vmcnt(4)" ::: "memory"); }
    __builtin_amdgcn_sched_barrier(0);
    __builtin_amdgcn_s_barrier();
    __builtin_amdgcn_sched_barrier(0);

    // rv loads issued early; consumed only at iter end (latency hidden by MFMA).
    float rv0 = rjc[j * JT + fr];
    float rv1 = rjc[j * JT + 16 + fr];
    __builtin_amdgcn_sched_barrier(0);
    if (j + 2 < NJ) {
      int sb = rb + 2; if (sb >= 3) sb -= 3;
      STAGE(sb, j + 2);
    }
    __builtin_amdgcn_sched_barrier(0);

    f32x4 acc[4][2];
#pragma unroll
    for (int m = 0; m < 4; ++m)
#pragma unroll
      for (int n = 0; n < 2; ++n) acc[m][n] = (f32x4){0.f, 0.f, 0.f, 0.f};

    const unsigned short* B = &Bt[rb][0];
    // Fragment address: chunk (n*8+ks)*512 shorts + fr*32 + g4*8 shorts.
#define BADDR(n, ks) (((n) * 8 + (ks)) * 512 + fr * 32 + g4 * 8)
    // 2-deep B-fragment prefetch ring (indices compile-time after full unroll).
    bf16x8 pb0[3], pb1[3];
    pb0[0] = *reinterpret_cast<const bf16x8*>(&B[BADDR(0, 0)]);
    pb1[0] = *reinterpret_cast<const bf16x8*>(&B[BADDR(1, 0)]);
    pb0[1] = *reinterpret_cast<const bf16x8*>(&B[BADDR(0, 1)]);
    pb1[1] = *reinterpret_cast<const bf16x8*>(&B[BADDR(1, 1)]);

    __builtin_amdgcn_s_setprio(1);
    __builtin_amdgcn_sched_barrier(0);
#pragma unroll
    for (int ks = 0; ks < 8; ++ks) {
      const int cs = ks % 3;
      const int ns = (ks + 2) % 3;
      if (ks < 6) {
        pb0[ns] = *reinterpret_cast<const bf16x8*>(&B[BADDR(0, ks + 2)]);
        pb1[ns] = *reinterpret_cast<const bf16x8*>(&B[BADDR(1, ks + 2)]);
      }
#pragma unroll
      for (int m = 0; m < 4; ++m) {
        acc[m][0] = __builtin_amdgcn_mfma_f32_16x16x32_bf16(afr[m][ks], pb0[cs], acc[m][0], 0, 0, 0);
        acc[m][1] = __builtin_amdgcn_mfma_f32_16x16x32_bf16(afr[m][ks], pb1[cs], acc[m][1], 0, 0, 0);
      }
      // Pin emission: 2 ds_reads ride under each 8-MFMA cluster.
      if (ks < 6) {
        __builtin_amdgcn_sched_group_barrier(0x100, 2, 0);  // 2 DS_READ
        __builtin_amdgcn_sched_group_barrier(0x008, 8, 0);  // 8 MFMA
      } else {
        __builtin_amdgcn_sched_group_barrier(0x008, 8, 0);  // 8 MFMA
      }
    }
    __builtin_amdgcn_sched_barrier(0);
#undef BADDR
    __builtin_amdgcn_s_setprio(0);

    // fold: val = rv - 2*dot ; running min
#pragma unroll
    for (int m = 0; m < 4; ++m)
#pragma unroll
      for (int r = 0; r < 4; ++r) {
        mn[m][r] = fminf(mn[m][r], fmaf(-2.f, acc[m][0][r], rv0));
        mn[m][r] = fminf(mn[m][r], fmaf(-2.f, acc[m][1][r], rv1));
      }
    rb = rb + 1; if (rb >= 3) rb -= 3;
  }
#undef STAGE

  // Row-min over chunk: reduce min over the 16 fr-lanes, then one atomic per row.
#pragma unroll
  for (int m = 0; m < 4; ++m)
#pragma unroll
    for (int r = 0; r < 4; ++r) {
      float v = mn[m][r];
#pragma unroll
      for (int s = 1; s < 16; s <<= 1) v = fminf(v, __shfl_xor(v, s, 64));
      if (fr == 0) {
        int row = brow + w * 64 + m * 16 + g4 * 4 + r;
        atomicMin(&rowmin[row], enc_f(v));
      }
    }
}

__global__ __launch_bounds__(256) void finish_kernel(
    const float* __restrict__ x2, const unsigned int* __restrict__ rowmin,
    const float* __restrict__ psi, float* __restrict__ out) {
  int tid = threadIdx.x;
  double s0 = 0.0, s1 = 0.0;
  for (int i = tid; i < N_ROWS; i += 256) {
    s0 += (double)x2[i] + (double)dec_f(rowmin[i]);
    s1 += (double)psi[i];
  }
  __shared__ double sm0[4], sm1[4];
#pragma unroll
  for (int m = 1; m < 64; m <<= 1) { s0 += __shfl_xor(s0, m, 64); s1 += __shfl_xor(s1, m, 64); }
  if ((tid & 63) == 0) { sm0[tid >> 6] = s0; sm1[tid >> 6] = s1; }
  __syncthreads();
  if (tid == 0) {
    out[0] = (float)((sm0[0] + sm0[1] + sm0[2] + sm0[3]) / (double)N_ROWS);
    out[1] = (float)((sm1[0] + sm1[1] + sm1[2] + sm1[3]) / (double)M_ROWS);
  }
}

extern "C" void kernel_launch(void* const* d_in, const int* in_sizes, int n_in,
                              void* d_out, int out_size, void* d_ws, size_t ws_size,
                              hipStream_t stream) {
  const float* x   = (const float*)d_in[0];
  const float* y   = (const float*)d_in[1];
  const float* psi = (const float*)d_in[2];
  float* out = (float*)d_out;

  char* ws = (char*)d_ws;
  unsigned short* xb = (unsigned short*)ws;                                  // 8 MB
  unsigned short* yb = (unsigned short*)(ws + (size_t)N_ROWS * DIM * 2);     // 8 MB
  float* x2 = (float*)(ws + (size_t)(N_ROWS + M_ROWS) * DIM * 2);            // 64 KB
  float* rj = x2 + N_ROWS;                                                   // 64 KB (y2 - psi)
  unsigned int* rowmin = (unsigned int*)(rj + M_ROWS);                       // 64 KB

  prep_kernel<<<(N_ROWS + M_ROWS) / 4, 256, 0, stream>>>(x, y, psi, xb, yb, x2, rj, rowmin);
  gemm_min_kernel<<<(N_ROWS / 256) * 8, 256, 0, stream>>>(xb, yb, rj, rowmin);
  finish_kernel<<<1, 256, 0, stream>>>(x2, rowmin, psi, out);
}